// Round 2
// baseline (368.014 us; speedup 1.0000x reference)
//
#include <hip/hip_runtime.h>

#define K_2RPI   1.1283791670955126f   // 2/sqrt(pi)
#define LN2F     0.6931471805599453f
#define PI_2F    1.5707963267948966f

// atan minimax odd poly on [0,1], max err ~2e-6 (checked at x=1: 0.78539650 vs 0.78539816)
__device__ __forceinline__ float atan_poly01(float r) {
    const float r2 = r * r;
    float p = fmaf(r2, -0.01172120f, 0.05265332f);
    p = fmaf(r2, p, -0.11643287f);
    p = fmaf(r2, p,  0.19354346f);
    p = fmaf(r2, p, -0.33262347f);
    p = fmaf(r2, p,  0.99997726f);
    return p * r;
}

template <int NT>
__global__ __launch_bounds__(256)
void chiplet_thermal_kernel(const float* __restrict__ x,  const float* __restrict__ y,
                            const float* __restrict__ cx, const float* __restrict__ cy,
                            const float* __restrict__ cw, const float* __restrict__ chh,
                            const float* __restrict__ cp,
                            const float* __restrict__ pA, const float* __restrict__ pa,
                            const float* __restrict__ pB,
                            const float* __restrict__ lx, const float* __restrict__ ly,
                            float* __restrict__ out, int n_rt, int G2)
{
    const int b = blockIdx.y;
    const int g = blockIdx.x * blockDim.x + threadIdx.x;
    if (g >= G2) return;
    const int idx = b * G2 + g;

    const float xv   = x[idx];
    const float yv   = y[idx];
    const float Av   = pA[0];
    const float av   = pa[0];
    const float Boff = pB[0];
    const float a2   = av * av;
    const float aa   = fabsf(av);

    const int n = (NT > 0) ? NT : n_rt;

    float acc     = 0.0f;
    float sumPiA  = 0.0f;

#pragma unroll
    for (int i = 0; i < n; ++i) {
        // ---- block-uniform chiplet parameters (scalar loads) ----
        const float rlx = __builtin_amdgcn_rcpf(lx[i]);
        const float rly = __builtin_amdgcn_rcpf(ly[i]);
        const float cxi = cx[b * n + i];
        const float cyi = cy[b * n + i];
        const float w2  = 0.5f * cw[b * n + i];
        const float h2  = 0.5f * chh[b * n + i];
        const float PiA = cp[b * n + i] * Av;

        // b = (w2 - sx*dx)/lx, dx = x - cx:
        //   sx=+1: (w2+cx)/lx - x/lx    sx=-1: (w2-cx)/lx + x/lx
        const float xr = xv * rlx;
        const float yr = yv * rly;
        const float b1 = (w2 + cxi) * rlx - xr;
        const float b2 = (w2 - cxi) * rlx + xr;
        const float c1 = (h2 + cyi) * rly - yr;
        const float c2 = (h2 - cyi) * rly + yr;

        const float bsq1 = b1 * b1, bsq2 = b2 * b2;
        const float csq1 = c1 * c1, csq2 = c2 * c2;
        const float B1 = a2 + bsq1, B2 = a2 + bsq2;
        const float C1 = a2 + csq1, C2 = a2 + csq2;

        // delta^2 = a2 + b^2 + c^2 = B + csq
        const float d11 = __builtin_amdgcn_sqrtf(B1 + csq1);
        const float d12 = __builtin_amdgcn_sqrtf(B1 + csq2);
        const float d21 = __builtin_amdgcn_sqrtf(B2 + csq1);
        const float d22 = __builtin_amdgcn_sqrtf(B2 + csq2);

        // ---- merged log terms: 4 logs instead of 12 ----
        // sum_corners(t1+t2) = ln2 * [ b1*log2((c1+d11)(c2+d12)/B1)
        //                            + b2*log2((c1+d21)(c2+d22)/B2)
        //                            + c1*log2((b1+d11)(b2+d21)/C1)
        //                            + c2*log2((b1+d12)(b2+d22)/C2) ]
        const float lpb1 = (c1 + d11) * (c2 + d12) * __builtin_amdgcn_rcpf(B1);
        const float lpb2 = (c1 + d21) * (c2 + d22) * __builtin_amdgcn_rcpf(B2);
        const float lpc1 = (b1 + d11) * (b2 + d21) * __builtin_amdgcn_rcpf(C1);
        const float lpc2 = (b1 + d12) * (b2 + d22) * __builtin_amdgcn_rcpf(C2);

        float logsum;
        logsum = b1 * __log2f(lpb1);
        logsum = fmaf(b2, __log2f(lpb2), logsum);
        logsum = fmaf(c1, __log2f(lpc1), logsum);
        logsum = fmaf(c2, __log2f(lpc2), logsum);

        // ---- atan terms: a*atan(b*c/(a*delta)) is even in a -> |a| ----
        float atansum = 0.0f;
        {
            const float num = b1 * c1, an = fabsf(num), ad = aa * d11;
            const float hi = fmaxf(an, ad), lo = fminf(an, ad);
            const float p = atan_poly01(lo * __builtin_amdgcn_rcpf(hi));
            const float ang = (an > ad) ? (PI_2F - p) : p;
            atansum += __builtin_copysignf(ang, num);
        }
        {
            const float num = b1 * c2, an = fabsf(num), ad = aa * d12;
            const float hi = fmaxf(an, ad), lo = fminf(an, ad);
            const float p = atan_poly01(lo * __builtin_amdgcn_rcpf(hi));
            const float ang = (an > ad) ? (PI_2F - p) : p;
            atansum += __builtin_copysignf(ang, num);
        }
        {
            const float num = b2 * c1, an = fabsf(num), ad = aa * d21;
            const float hi = fmaxf(an, ad), lo = fminf(an, ad);
            const float p = atan_poly01(lo * __builtin_amdgcn_rcpf(hi));
            const float ang = (an > ad) ? (PI_2F - p) : p;
            atansum += __builtin_copysignf(ang, num);
        }
        {
            const float num = b2 * c2, an = fabsf(num), ad = aa * d22;
            const float hi = fmaxf(an, ad), lo = fminf(an, ad);
            const float p = atan_poly01(lo * __builtin_amdgcn_rcpf(hi));
            const float ang = (an > ad) ? (PI_2F - p) : p;
            atansum += __builtin_copysignf(ang, num);
        }

        // F-sum for this chiplet: K*(ln2*logsum - aa*atansum); weight by PiA
        acc = fmaf(PiA * (K_2RPI * LN2F), logsum, acc);
        acc = fmaf(-(PiA * K_2RPI * aa), atansum, acc);
        sumPiA += PiA;
    }

    // + PiA_i * B_off summed over chiplets
    out[idx] = fmaf(sumPiA, Boff, acc);
}

extern "C" void kernel_launch(void* const* d_in, const int* in_sizes, int n_in,
                              void* d_out, int out_size, void* d_ws, size_t ws_size,
                              hipStream_t stream) {
    const float* x   = (const float*)d_in[0];
    const float* y   = (const float*)d_in[1];
    const float* cx  = (const float*)d_in[2];
    const float* cy  = (const float*)d_in[3];
    const float* cw  = (const float*)d_in[4];
    const float* chh = (const float*)d_in[5];
    const float* cp  = (const float*)d_in[6];
    const float* pA  = (const float*)d_in[7];
    const float* pa  = (const float*)d_in[8];
    const float* pB  = (const float*)d_in[9];
    const float* lx  = (const float*)d_in[10];
    const float* ly  = (const float*)d_in[11];
    float* out = (float*)d_out;

    const int N  = in_sizes[10];            // lx has N elements
    const int B  = in_sizes[2] / N;         // chiplets_x is (B, N)
    const int G2 = in_sizes[0] / B;         // x is (B, G2)

    dim3 block(256, 1, 1);
    dim3 grid((G2 + 255) / 256, B, 1);

    if (N == 16) {
        chiplet_thermal_kernel<16><<<grid, block, 0, stream>>>(
            x, y, cx, cy, cw, chh, cp, pA, pa, pB, lx, ly, out, N, G2);
    } else {
        chiplet_thermal_kernel<0><<<grid, block, 0, stream>>>(
            x, y, cx, cy, cw, chh, cp, pA, pa, pB, lx, ly, out, N, G2);
    }
}

// Round 6
// 331.687 us; speedup vs baseline: 1.1095x; 1.1095x over previous
//
#include <hip/hip_runtime.h>

#define K_2RPI   1.1283791670955126f   // 2/sqrt(pi)
#define LN2F     0.6931471805599453f
#define PI_2F    1.5707963267948966f

// atan minimax odd poly on [0,1], max err ~2e-6
__device__ __forceinline__ float atan_poly01(float r) {
    const float r2 = r * r;
    float p = fmaf(r2, -0.01172120f, 0.05265332f);
    p = fmaf(r2, p, -0.11643287f);
    p = fmaf(r2, p,  0.19354346f);
    p = fmaf(r2, p, -0.33262347f);
    p = fmaf(r2, p,  0.99997726f);
    return p * r;
}

// ---------------------------------------------------------------------------
// Pre-kernel: per-(b,i) uniform math, once total instead of once per thread.
// ws[(b*N+i)*8 + {0..7}] = U1, U2, V1, V2, rlx, rly, PL, PTn
// ws[B*N*8 + b]          = SPB[b] = B_off * A * sum_i cp[b,i]
// ---------------------------------------------------------------------------
__global__ void chiplet_pre_kernel(const float* __restrict__ cx, const float* __restrict__ cy,
                                   const float* __restrict__ cw, const float* __restrict__ chh,
                                   const float* __restrict__ cp,
                                   const float* __restrict__ pA, const float* __restrict__ pa,
                                   const float* __restrict__ pB,
                                   const float* __restrict__ lx, const float* __restrict__ ly,
                                   float* __restrict__ ws, int B, int N)
{
    const int t = blockIdx.x * blockDim.x + threadIdx.x;
    if (t >= B * N) return;
    const int b = t / N;
    const int i = t - b * N;

    const float Av   = pA[0];
    const float av   = pa[0];
    const float Boff = pB[0];
    const float aa   = fabsf(av);

    const float rlx = 1.0f / lx[i];
    const float rly = 1.0f / ly[i];
    const float w2  = 0.5f * cw[t];
    const float h2  = 0.5f * chh[t];
    const float cxi = cx[t];
    const float cyi = cy[t];
    const float PiA = cp[t] * Av;

    float* o = ws + (size_t)t * 8;
    o[0] = (w2 + cxi) * rlx;            // U1
    o[1] = (w2 - cxi) * rlx;            // U2
    o[2] = (h2 + cyi) * rly;            // V1
    o[3] = (h2 - cyi) * rly;            // V2
    o[4] = rlx;
    o[5] = rly;
    o[6] = PiA * (K_2RPI * LN2F);       // PL
    o[7] = -(PiA * K_2RPI * aa);        // PTn

    if (i == 0) {
        float s = 0.0f;
        for (int j = 0; j < N; ++j) s += cp[b * N + j];
        ws[(size_t)B * N * 8 + b] = s * Av * Boff;   // SPB[b]
    }
}

// ---------------------------------------------------------------------------
// Main kernel: one thread per output point.
// ---------------------------------------------------------------------------
template <int NT>
__global__ __launch_bounds__(256)
void chiplet_main_kernel(const float* __restrict__ x, const float* __restrict__ y,
                         const float* __restrict__ pa,
                         const float* __restrict__ ws,
                         float* __restrict__ out, int n_rt, int G2, int B)
{
    const int b = blockIdx.y;
    const int g = blockIdx.x * blockDim.x + threadIdx.x;
    if (g >= G2) return;
    const int idx = b * G2 + g;
    const int n = (NT > 0) ? NT : n_rt;

    const float xv = x[idx];
    const float yv = y[idx];
    const float av = pa[0];
    const float a2 = av * av;
    const float aa = fabsf(av);

    float acc = ws[(size_t)B * n * 8 + b];   // SPB[b] (uniform s_load)

#pragma unroll
    for (int i = 0; i < n; ++i) {
        const float* o = ws + (size_t)(b * n + i) * 8;   // uniform -> s_load_dwordx8
        const float U1  = o[0], U2  = o[1], V1 = o[2], V2 = o[3];
        const float rlx = o[4], rly = o[5], PL = o[6], PTn = o[7];

        const float xr = xv * rlx;
        const float yr = yv * rly;
        const float b1 = U1 - xr, b2 = U2 + xr;
        const float c1 = V1 - yr, c2 = V2 + yr;

        const float bsq1 = b1 * b1, bsq2 = b2 * b2;
        const float csq1 = c1 * c1, csq2 = c2 * c2;
        const float B1 = a2 + bsq1, B2 = a2 + bsq2;
        const float C1 = a2 + csq1, C2 = a2 + csq2;

        const float d11 = __builtin_amdgcn_sqrtf(B1 + csq1);
        const float d12 = __builtin_amdgcn_sqrtf(B1 + csq2);
        const float d21 = __builtin_amdgcn_sqrtf(B2 + csq1);
        const float d22 = __builtin_amdgcn_sqrtf(B2 + csq2);

        // ---- merged log terms (4 logs), single rcp for all 4 denominators ----
        const float nb1 = (c1 + d11) * (c2 + d12);
        const float nb2 = (c1 + d21) * (c2 + d22);
        const float nc1 = (b1 + d11) * (b2 + d21);
        const float nc2 = (b1 + d12) * (b2 + d22);

        const float m12 = B1 * B2, m34 = C1 * C2;
        const float R   = __builtin_amdgcn_rcpf(m12 * m34);
        const float R12 = R * m34, R34 = R * m12;
        const float rB1 = R12 * B2, rB2 = R12 * B1;
        const float rC1 = R34 * C2, rC2 = R34 * C1;

        float logsum =      b1 * __log2f(nb1 * rB1);
        logsum = fmaf(b2, __log2f(nb2 * rB2), logsum);
        logsum = fmaf(c1, __log2f(nc1 * rC1), logsum);
        logsum = fmaf(c2, __log2f(nc2 * rC2), logsum);

        // ---- atan terms, single rcp for all 4 range-reduction divisors ----
        const float n11 = b1 * c1, n12 = b1 * c2, n21 = b2 * c1, n22 = b2 * c2;
        const float ad11 = aa * d11, ad12 = aa * d12, ad21 = aa * d21, ad22 = aa * d22;

        const float h11 = fmaxf(fabsf(n11), ad11), l11 = fminf(fabsf(n11), ad11);
        const float h12 = fmaxf(fabsf(n12), ad12), l12 = fminf(fabsf(n12), ad12);
        const float h21 = fmaxf(fabsf(n21), ad21), l21 = fminf(fabsf(n21), ad21);
        const float h22 = fmaxf(fabsf(n22), ad22), l22 = fminf(fabsf(n22), ad22);

        const float hp12 = h11 * h12, hp34 = h21 * h22;
        const float HR   = __builtin_amdgcn_rcpf(hp12 * hp34);
        const float HR12 = HR * hp34, HR34 = HR * hp12;
        const float P11 = HR12 * h12, P12 = HR12 * h11;
        const float P21 = HR34 * h22, P22 = HR34 * h21;

        float atansum;
        {
            const float p   = atan_poly01(l11 * P11);
            const float ang = (fabsf(n11) > ad11) ? (PI_2F - p) : p;
            atansum = __builtin_copysignf(ang, n11);
        }
        {
            const float p   = atan_poly01(l12 * P12);
            const float ang = (fabsf(n12) > ad12) ? (PI_2F - p) : p;
            atansum += __builtin_copysignf(ang, n12);
        }
        {
            const float p   = atan_poly01(l21 * P21);
            const float ang = (fabsf(n21) > ad21) ? (PI_2F - p) : p;
            atansum += __builtin_copysignf(ang, n21);
        }
        {
            const float p   = atan_poly01(l22 * P22);
            const float ang = (fabsf(n22) > ad22) ? (PI_2F - p) : p;
            atansum += __builtin_copysignf(ang, n22);
        }

        acc = fmaf(PL,  logsum,  acc);
        acc = fmaf(PTn, atansum, acc);
    }

    out[idx] = acc;
}

extern "C" void kernel_launch(void* const* d_in, const int* in_sizes, int n_in,
                              void* d_out, int out_size, void* d_ws, size_t ws_size,
                              hipStream_t stream) {
    const float* x   = (const float*)d_in[0];
    const float* y   = (const float*)d_in[1];
    const float* cx  = (const float*)d_in[2];
    const float* cy  = (const float*)d_in[3];
    const float* cw  = (const float*)d_in[4];
    const float* chh = (const float*)d_in[5];
    const float* cp  = (const float*)d_in[6];
    const float* pA  = (const float*)d_in[7];
    const float* pa  = (const float*)d_in[8];
    const float* pB  = (const float*)d_in[9];
    const float* lx  = (const float*)d_in[10];
    const float* ly  = (const float*)d_in[11];
    float* out = (float*)d_out;
    float* ws  = (float*)d_ws;

    const int N  = in_sizes[10];            // lx has N elements
    const int B  = in_sizes[2] / N;         // chiplets_x is (B, N)
    const int G2 = in_sizes[0] / B;         // x is (B, G2)

    // precompute per-(b,i) uniforms
    {
        const int total = B * N;
        dim3 pb(256, 1, 1);
        dim3 pg((total + 255) / 256, 1, 1);
        chiplet_pre_kernel<<<pg, pb, 0, stream>>>(cx, cy, cw, chh, cp,
                                                  pA, pa, pB, lx, ly, ws, B, N);
    }

    dim3 block(256, 1, 1);
    dim3 grid((G2 + 255) / 256, B, 1);

    if (N == 16) {
        chiplet_main_kernel<16><<<grid, block, 0, stream>>>(x, y, pa, ws, out, N, G2, B);
    } else {
        chiplet_main_kernel<0><<<grid, block, 0, stream>>>(x, y, pa, ws, out, N, G2, B);
    }
}

// Round 8
// 265.266 us; speedup vs baseline: 1.3873x; 1.2504x over previous
//
#include <hip/hip_runtime.h>

#define K_2RPI   1.1283791670955126f   // 2/sqrt(pi)
#define LN2F     0.6931471805599453f
#define PI_2F    1.5707963267948966f
#define PIF      3.14159265358979323846f

// atan minimax odd poly on [0,1], max err ~2e-6
__device__ __forceinline__ float atan_poly01(float r) {
    const float r2 = r * r;
    float p = fmaf(r2, -0.01172120f, 0.05265332f);
    p = fmaf(r2, p, -0.11643287f);
    p = fmaf(r2, p,  0.19354346f);
    p = fmaf(r2, p, -0.33262347f);
    p = fmaf(r2, p,  0.99997726f);
    return p * r;
}

// ---------------------------------------------------------------------------
// Pre-kernel: per-(b,i) uniform math, a-NORMALIZED: F(a,b,c) = |a|*F(1,b/|a|,c/|a|).
// ws[(b*N+i)*8 + {0..7}] = U1,U2,V1,V2, rlxa, rlya, PL, PTn   (all /|a| scaled)
// ws[B*N*8 + b]          = SPB[b] = B_off * A * sum_i cp[b,i]
// ---------------------------------------------------------------------------
__global__ void chiplet_pre_kernel(const float* __restrict__ cx, const float* __restrict__ cy,
                                   const float* __restrict__ cw, const float* __restrict__ chh,
                                   const float* __restrict__ cp,
                                   const float* __restrict__ pA, const float* __restrict__ pa,
                                   const float* __restrict__ pB,
                                   const float* __restrict__ lx, const float* __restrict__ ly,
                                   float* __restrict__ ws, int B, int N)
{
    const int t = blockIdx.x * blockDim.x + threadIdx.x;
    if (t >= B * N) return;
    const int b = t / N;
    const int i = t - b * N;

    const float Av   = pA[0];
    const float av   = pa[0];
    const float Boff = pB[0];
    const float aa   = fabsf(av);

    const float rlxa = 1.0f / (lx[i] * aa);
    const float rlya = 1.0f / (ly[i] * aa);
    const float w2  = 0.5f * cw[t];
    const float h2  = 0.5f * chh[t];
    const float cxi = cx[t];
    const float cyi = cy[t];
    const float PiA = cp[t] * Av;

    float* o = ws + (size_t)t * 8;
    o[0] = (w2 + cxi) * rlxa;           // U1
    o[1] = (w2 - cxi) * rlxa;           // U2
    o[2] = (h2 + cyi) * rlya;           // V1
    o[3] = (h2 - cyi) * rlya;           // V2
    o[4] = rlxa;
    o[5] = rlya;
    o[6] = PiA * (K_2RPI * LN2F) * aa;  // PL  (weights b,c carry the |a| scale)
    o[7] = -(PiA * K_2RPI) * aa;        // PTn

    if (i == 0) {
        float s = 0.0f;
        for (int j = 0; j < N; ++j) s += cp[b * N + j];
        ws[(size_t)B * N * 8 + b] = s * Av * Boff;   // SPB[b]
    }
}

// ---------------------------------------------------------------------------
// Main kernel: one thread per output point. a==1 internally.
// Log terms:  sum_corners(t1+t2) = ln2*[ b1*log2((c2+d12)/(d11-c1))
//                                      + b2*log2((c2+d22)/(d21-c1))
//                                      + c1*log2((b2+d21)/(d11-b1))
//                                      + c2*log2((b2+d22)/(d12-b1)) ]
//   using (1+b^2) = d^2-c^2 = (d-c)(d+c) to fold the denominator.
// Atan terms: sum atan(n/d) = atan2 of complex product (d + i n) pairs;
//   each pair-sum in (-pi,pi) since each |theta| < pi/2.
// ---------------------------------------------------------------------------
template <int NT>
__global__ __launch_bounds__(256)
void chiplet_main_kernel(const float* __restrict__ x, const float* __restrict__ y,
                         const float* __restrict__ ws,
                         float* __restrict__ out, int n_rt, int G2, int B)
{
    const int b = blockIdx.y;
    const int g = blockIdx.x * blockDim.x + threadIdx.x;
    if (g >= G2) return;
    const int idx = b * G2 + g;
    const int n = (NT > 0) ? NT : n_rt;

    const float xv = x[idx];
    const float yv = y[idx];

    float acc = ws[(size_t)B * n * 8 + b];   // SPB[b] (uniform s_load)

#pragma unroll
    for (int i = 0; i < n; ++i) {
        const float* o = ws + (size_t)(b * n + i) * 8;   // uniform -> s_load_dwordx8
        const float U1  = o[0], U2  = o[1], V1 = o[2], V2 = o[3];
        const float rlx = o[4], rly = o[5], PL = o[6], PTn = o[7];

        const float b1 = fmaf(-xv, rlx, U1);
        const float b2 = fmaf( xv, rlx, U2);
        const float c1 = fmaf(-yv, rly, V1);
        const float c2 = fmaf( yv, rly, V2);

        const float sb1 = fmaf(b1, b1, 1.0f);   // 1 + b^2
        const float sb2 = fmaf(b2, b2, 1.0f);
        const float cq1 = c1 * c1;
        const float cq2 = c2 * c2;

        const float d11 = __builtin_amdgcn_sqrtf(sb1 + cq1);
        const float d12 = __builtin_amdgcn_sqrtf(sb1 + cq2);
        const float d21 = __builtin_amdgcn_sqrtf(sb2 + cq1);
        const float d22 = __builtin_amdgcn_sqrtf(sb2 + cq2);

        // ---- log terms: 4 logs, ratio form, single rcp for 4 denominators ----
        const float nu1 = c2 + d12, nu2 = c2 + d22;
        const float nu3 = b2 + d21, nu4 = b2 + d22;
        const float de1 = d11 - c1, de2 = d21 - c1;
        const float de3 = d11 - b1, de4 = d12 - b1;

        const float p12 = de1 * de2, p34 = de3 * de4;
        const float R   = __builtin_amdgcn_rcpf(p12 * p34);
        const float R12 = R * p34, R34 = R * p12;
        const float r1 = R12 * de2, r2 = R12 * de1;
        const float r3 = R34 * de4, r4 = R34 * de3;

        float logsum =      b1 * __log2f(nu1 * r1);
        logsum = fmaf(b2, __log2f(nu2 * r2), logsum);
        logsum = fmaf(c1, __log2f(nu3 * r3), logsum);
        logsum = fmaf(c2, __log2f(nu4 * r4), logsum);

        // ---- atan terms via complex pair products: (d11+i n11)(d12+i n12) ----
        const float n11 = b1 * c1, n12 = b1 * c2;
        const float n21 = b2 * c1, n22 = b2 * c2;

        const float reA = fmaf(-n11, n12, d11 * d12);
        const float imA = fmaf( d11, n12, n11 * d12);
        const float reB = fmaf(-n21, n22, d21 * d22);
        const float imB = fmaf( d21, n22, n21 * d22);

        // two full-range atan2, sharing one rcp
        const float ayA = fabsf(imA), axA = fabsf(reA);
        const float ayB = fabsf(imB), axB = fabsf(reB);
        const float hA = fmaxf(ayA, axA), lA = fminf(ayA, axA);
        const float hB = fmaxf(ayB, axB), lB = fminf(ayB, axB);

        const float R2 = __builtin_amdgcn_rcpf(hA * hB);
        const float tA = lA * (R2 * hB);
        const float tB = lB * (R2 * hA);

        const float pA_ = atan_poly01(tA);
        const float pB_ = atan_poly01(tB);

        float angA = (ayA > axA) ? (PI_2F - pA_) : pA_;
        angA = (reA < 0.0f) ? (PIF - angA) : angA;
        angA = __builtin_copysignf(angA, imA);

        float angB = (ayB > axB) ? (PI_2F - pB_) : pB_;
        angB = (reB < 0.0f) ? (PIF - angB) : angB;
        angB = __builtin_copysignf(angB, imB);

        const float atansum = angA + angB;

        acc = fmaf(PL,  logsum,  acc);
        acc = fmaf(PTn, atansum, acc);
    }

    out[idx] = acc;
}

extern "C" void kernel_launch(void* const* d_in, const int* in_sizes, int n_in,
                              void* d_out, int out_size, void* d_ws, size_t ws_size,
                              hipStream_t stream) {
    const float* x   = (const float*)d_in[0];
    const float* y   = (const float*)d_in[1];
    const float* cx  = (const float*)d_in[2];
    const float* cy  = (const float*)d_in[3];
    const float* cw  = (const float*)d_in[4];
    const float* chh = (const float*)d_in[5];
    const float* cp  = (const float*)d_in[6];
    const float* pA  = (const float*)d_in[7];
    const float* pa  = (const float*)d_in[8];
    const float* pB  = (const float*)d_in[9];
    const float* lx  = (const float*)d_in[10];
    const float* ly  = (const float*)d_in[11];
    float* out = (float*)d_out;
    float* ws  = (float*)d_ws;

    const int N  = in_sizes[10];            // lx has N elements
    const int B  = in_sizes[2] / N;         // chiplets_x is (B, N)
    const int G2 = in_sizes[0] / B;         // x is (B, G2)

    // precompute per-(b,i) uniforms (a-normalized)
    {
        const int total = B * N;
        dim3 pb(256, 1, 1);
        dim3 pg((total + 255) / 256, 1, 1);
        chiplet_pre_kernel<<<pg, pb, 0, stream>>>(cx, cy, cw, chh, cp,
                                                  pA, pa, pB, lx, ly, ws, B, N);
    }

    dim3 block(256, 1, 1);
    dim3 grid((G2 + 255) / 256, B, 1);

    if (N == 16) {
        chiplet_main_kernel<16><<<grid, block, 0, stream>>>(x, y, ws, out, N, G2, B);
    } else {
        chiplet_main_kernel<0><<<grid, block, 0, stream>>>(x, y, ws, out, N, G2, B);
    }
}

// Round 13
// 264.061 us; speedup vs baseline: 1.3937x; 1.0046x over previous
//
#include <hip/hip_runtime.h>

#define K_2RPI   1.1283791670955126f   // 2/sqrt(pi)
#define LN2F     0.6931471805599453f
#define PI_2F    1.5707963267948966f
#define PIF      3.14159265358979323846f

// atan minimax odd poly on [0,1]: FULL A&S 4.4.49 (5 terms, degree-9), |err| <= 1e-5
__device__ __forceinline__ float atan_poly01(float r) {
    const float r2 = r * r;
    float p = fmaf(r2,  0.0208351f, -0.0851330f);
    p = fmaf(r2, p,  0.1801410f);
    p = fmaf(r2, p, -0.3302995f);
    p = fmaf(r2, p,  0.9998660f);
    return p * r;
}

// ---------------------------------------------------------------------------
// Pre-kernel: per-(b,i) uniform math, a-NORMALIZED: F(a,b,c) = |a|*F(1,b/|a|,c/|a|).
// ws[(b*N+i)*8 + {0..7}] = U1,U2,V1,V2, rlxa, rlya, PL, PTn   (all /|a| scaled)
// ws[B*N*8 + b]          = SPB[b] = B_off * A * sum_i cp[b,i]
// ---------------------------------------------------------------------------
__global__ void chiplet_pre_kernel(const float* __restrict__ cx, const float* __restrict__ cy,
                                   const float* __restrict__ cw, const float* __restrict__ chh,
                                   const float* __restrict__ cp,
                                   const float* __restrict__ pA, const float* __restrict__ pa,
                                   const float* __restrict__ pB,
                                   const float* __restrict__ lx, const float* __restrict__ ly,
                                   float* __restrict__ ws, int B, int N)
{
    const int t = blockIdx.x * blockDim.x + threadIdx.x;
    if (t >= B * N) return;
    const int b = t / N;
    const int i = t - b * N;

    const float Av   = pA[0];
    const float av   = pa[0];
    const float Boff = pB[0];
    const float aa   = fabsf(av);

    const float rlxa = 1.0f / (lx[i] * aa);
    const float rlya = 1.0f / (ly[i] * aa);
    const float w2  = 0.5f * cw[t];
    const float h2  = 0.5f * chh[t];
    const float cxi = cx[t];
    const float cyi = cy[t];
    const float PiA = cp[t] * Av;

    float* o = ws + (size_t)t * 8;
    o[0] = (w2 + cxi) * rlxa;           // U1
    o[1] = (w2 - cxi) * rlxa;           // U2
    o[2] = (h2 + cyi) * rlya;           // V1
    o[3] = (h2 - cyi) * rlya;           // V2
    o[4] = rlxa;
    o[5] = rlya;
    o[6] = PiA * (K_2RPI * LN2F) * aa;  // PL  (weights b,c carry the |a| scale)
    o[7] = -(PiA * K_2RPI) * aa;        // PTn

    if (i == 0) {
        float s = 0.0f;
        for (int j = 0; j < N; ++j) s += cp[b * N + j];
        ws[(size_t)B * N * 8 + b] = s * Av * Boff;   // SPB[b]
    }
}

// ---------------------------------------------------------------------------
// Main kernel: one thread per output point. a==1 internally.
// Log terms (ratio form via (1+b^2) = (d-c)(d+c)):
//   sum(t1+t2) = ln2*[ b1*log2((c2+d12)/(d11-c1)) + b2*log2((c2+d22)/(d21-c1))
//              + c1*log2((b2+d21)/(d11-b1)) + c2*log2((b2+d22)/(d12-b1)) ]
// Atan terms: sum atan(n/d) = atan2 of complex pair products (d + i n);
//   each pair-sum in (-pi,pi) since each |theta| < pi/2.
// Single v_rcp serves all 4 log denominators AND both atan range reductions.
// ---------------------------------------------------------------------------
template <int NT>
__global__ __launch_bounds__(256)
void chiplet_main_kernel(const float* __restrict__ x, const float* __restrict__ y,
                         const float* __restrict__ ws,
                         float* __restrict__ out, int n_rt, int G2, int B)
{
    const int b = blockIdx.y;
    const int g = blockIdx.x * blockDim.x + threadIdx.x;
    if (g >= G2) return;
    const int idx = b * G2 + g;
    const int n = (NT > 0) ? NT : n_rt;

    const float xv = x[idx];
    const float yv = y[idx];

    float acc = ws[(size_t)B * n * 8 + b];   // SPB[b] (uniform s_load)

#pragma unroll
    for (int i = 0; i < n; ++i) {
        const float* o = ws + (size_t)(b * n + i) * 8;   // uniform -> s_load_dwordx8
        const float U1  = o[0], U2  = o[1], V1 = o[2], V2 = o[3];
        const float rlx = o[4], rly = o[5], PL = o[6], PTn = o[7];

        const float b1 = fmaf(-xv, rlx, U1);
        const float b2 = fmaf( xv, rlx, U2);
        const float c1 = fmaf(-yv, rly, V1);
        const float c2 = fmaf( yv, rly, V2);

        const float sb1 = fmaf(b1, b1, 1.0f);   // 1 + b^2
        const float sb2 = fmaf(b2, b2, 1.0f);
        const float cq1 = c1 * c1;
        const float cq2 = c2 * c2;

        const float d11 = __builtin_amdgcn_sqrtf(sb1 + cq1);
        const float d12 = __builtin_amdgcn_sqrtf(sb1 + cq2);
        const float d21 = __builtin_amdgcn_sqrtf(sb2 + cq1);
        const float d22 = __builtin_amdgcn_sqrtf(sb2 + cq2);

        // ---- atan pair products first (to form H for the shared rcp) ----
        const float n11 = b1 * c1, n12 = b1 * c2;
        const float n21 = b2 * c1, n22 = b2 * c2;

        const float reA = fmaf(-n11, n12, d11 * d12);
        const float imA = fmaf( d11, n12, n11 * d12);
        const float reB = fmaf(-n21, n22, d21 * d22);
        const float imB = fmaf( d21, n22, n21 * d22);

        const float ayA = fabsf(imA), axA = fabsf(reA);
        const float ayB = fabsf(imB), axB = fabsf(reB);
        const float hA = fmaxf(ayA, axA), lA = fminf(ayA, axA);
        const float hB = fmaxf(ayB, axB), lB = fminf(ayB, axB);

        // ---- log numerators/denominators ----
        const float nu1 = c2 + d12, nu2 = c2 + d22;
        const float nu3 = b2 + d21, nu4 = b2 + d22;
        const float de1 = d11 - c1, de2 = d21 - c1;
        const float de3 = d11 - b1, de4 = d12 - b1;

        const float p12 = de1 * de2, p34 = de3 * de4;

        // ---- ONE rcp for everything ----
        const float G = p12 * p34;
        const float H = hA * hB;
        const float RC = __builtin_amdgcn_rcpf(G * H);
        const float R  = RC * H;          // 1/G
        const float R2 = RC * G;          // 1/H

        const float R12 = R * p34, R34 = R * p12;
        const float r1 = R12 * de2, r2 = R12 * de1;
        const float r3 = R34 * de4, r4 = R34 * de3;

        float logsum =      b1 * __log2f(nu1 * r1);
        logsum = fmaf(b2, __log2f(nu2 * r2), logsum);
        logsum = fmaf(c1, __log2f(nu3 * r3), logsum);
        logsum = fmaf(c2, __log2f(nu4 * r4), logsum);

        const float tA = lA * (R2 * hB);
        const float tB = lB * (R2 * hA);

        const float pA_ = atan_poly01(tA);
        const float pB_ = atan_poly01(tB);

        float angA = (ayA > axA) ? (PI_2F - pA_) : pA_;
        angA = (reA < 0.0f) ? (PIF - angA) : angA;
        angA = __builtin_copysignf(angA, imA);

        float angB = (ayB > axB) ? (PI_2F - pB_) : pB_;
        angB = (reB < 0.0f) ? (PIF - angB) : angB;
        angB = __builtin_copysignf(angB, imB);

        const float atansum = angA + angB;

        acc = fmaf(PL,  logsum,  acc);
        acc = fmaf(PTn, atansum, acc);
    }

    out[idx] = acc;
}

extern "C" void kernel_launch(void* const* d_in, const int* in_sizes, int n_in,
                              void* d_out, int out_size, void* d_ws, size_t ws_size,
                              hipStream_t stream) {
    const float* x   = (const float*)d_in[0];
    const float* y   = (const float*)d_in[1];
    const float* cx  = (const float*)d_in[2];
    const float* cy  = (const float*)d_in[3];
    const float* cw  = (const float*)d_in[4];
    const float* chh = (const float*)d_in[5];
    const float* cp  = (const float*)d_in[6];
    const float* pA  = (const float*)d_in[7];
    const float* pa  = (const float*)d_in[8];
    const float* pB  = (const float*)d_in[9];
    const float* lx  = (const float*)d_in[10];
    const float* ly  = (const float*)d_in[11];
    float* out = (float*)d_out;
    float* ws  = (float*)d_ws;

    const int N  = in_sizes[10];            // lx has N elements
    const int B  = in_sizes[2] / N;         // chiplets_x is (B, N)
    const int G2 = in_sizes[0] / B;         // x is (B, G2)

    // precompute per-(b,i) uniforms (a-normalized)
    {
        const int total = B * N;
        dim3 pb(256, 1, 1);
        dim3 pg((total + 255) / 256, 1, 1);
        chiplet_pre_kernel<<<pg, pb, 0, stream>>>(cx, cy, cw, chh, cp,
                                                  pA, pa, pB, lx, ly, ws, B, N);
    }

    dim3 block(256, 1, 1);
    dim3 grid((G2 + 255) / 256, B, 1);

    if (N == 16) {
        chiplet_main_kernel<16><<<grid, block, 0, stream>>>(x, y, ws, out, N, G2, B);
    } else {
        chiplet_main_kernel<0><<<grid, block, 0, stream>>>(x, y, ws, out, N, G2, B);
    }
}

// Round 14
// 241.382 us; speedup vs baseline: 1.5246x; 1.0940x over previous
//
#include <hip/hip_runtime.h>

#define K_2RPI   1.1283791670955126f   // 2/sqrt(pi)
#define LN2F     0.6931471805599453f
#define PI_2F    1.5707963267948966f
#define PIF      3.14159265358979323846f

// atan minimax odd poly on [0,1]: FULL A&S 4.4.49 (5 terms, degree-9), |err| <= 1e-5
__device__ __forceinline__ float atan_poly01(float r) {
    const float r2 = r * r;
    float p = fmaf(r2,  0.0208351f, -0.0851330f);
    p = fmaf(r2, p,  0.1801410f);
    p = fmaf(r2, p, -0.3302995f);
    p = fmaf(r2, p,  0.9998660f);
    return p * r;
}

// ---------------------------------------------------------------------------
// Pre-kernel: per-(b,i) uniform math, a-NORMALIZED: F(a,b,c) = |a|*F(1,b/|a|,c/|a|).
// ws[(b*N+i)*8 + {0..7}] = U1,U2,V1,V2, rlxa, rlya, PL, PTn   (all /|a| scaled)
// ws[B*N*8 + b]          = SPB[b] = B_off * A * sum_i cp[b,i]
// ---------------------------------------------------------------------------
__global__ void chiplet_pre_kernel(const float* __restrict__ cx, const float* __restrict__ cy,
                                   const float* __restrict__ cw, const float* __restrict__ chh,
                                   const float* __restrict__ cp,
                                   const float* __restrict__ pA, const float* __restrict__ pa,
                                   const float* __restrict__ pB,
                                   const float* __restrict__ lx, const float* __restrict__ ly,
                                   float* __restrict__ ws, int B, int N)
{
    const int t = blockIdx.x * blockDim.x + threadIdx.x;
    if (t >= B * N) return;
    const int b = t / N;
    const int i = t - b * N;

    const float Av   = pA[0];
    const float av   = pa[0];
    const float Boff = pB[0];
    const float aa   = fabsf(av);

    const float rlxa = 1.0f / (lx[i] * aa);
    const float rlya = 1.0f / (ly[i] * aa);
    const float w2  = 0.5f * cw[t];
    const float h2  = 0.5f * chh[t];
    const float cxi = cx[t];
    const float cyi = cy[t];
    const float PiA = cp[t] * Av;

    float* o = ws + (size_t)t * 8;
    o[0] = (w2 + cxi) * rlxa;           // U1
    o[1] = (w2 - cxi) * rlxa;           // U2
    o[2] = (h2 + cyi) * rlya;           // V1
    o[3] = (h2 - cyi) * rlya;           // V2
    o[4] = rlxa;
    o[5] = rlya;
    o[6] = PiA * (K_2RPI * LN2F) * aa;  // PL  (weights b,c carry the |a| scale)
    o[7] = -(PiA * K_2RPI) * aa;        // PTn

    if (i == 0) {
        float s = 0.0f;
        for (int j = 0; j < N; ++j) s += cp[b * N + j];
        ws[(size_t)B * N * 8 + b] = s * Av * Boff;   // SPB[b]
    }
}

// ---------------------------------------------------------------------------
// Main kernel: TWO grid points per thread (float2), shared per-chiplet uniforms.
// a==1 internally (a-normalized). Log ratio form + complex-pair atan,
// one v_rcp per point per chiplet.
// ---------------------------------------------------------------------------
template <int NT>
__global__ __launch_bounds__(256)
void chiplet_main_kernel(const float* __restrict__ x, const float* __restrict__ y,
                         const float* __restrict__ ws,
                         float* __restrict__ out, int n_rt, int G2, int B)
{
    const int b  = blockIdx.y;
    const int g  = blockIdx.x * blockDim.x + threadIdx.x;   // pair index
    const int half = G2 >> 1;
    if (g >= half) return;
    const int pidx = b * half + g;
    const int n = (NT > 0) ? NT : n_rt;

    const float2 xv2 = ((const float2*)x)[pidx];
    const float2 yv2 = ((const float2*)y)[pidx];
    const float xv[2] = { xv2.x, xv2.y };
    const float yv[2] = { yv2.x, yv2.y };

    const float spb = ws[(size_t)B * n * 8 + b];
    float acc[2] = { spb, spb };

#pragma unroll
    for (int i = 0; i < n; ++i) {
        const float* o = ws + (size_t)(b * n + i) * 8;   // uniform -> s_load_dwordx8
        const float U1  = o[0], U2  = o[1], V1 = o[2], V2 = o[3];
        const float rlx = o[4], rly = o[5], PL = o[6], PTn = o[7];

#pragma unroll
        for (int k = 0; k < 2; ++k) {
            const float b1 = fmaf(-xv[k], rlx, U1);
            const float b2 = fmaf( xv[k], rlx, U2);
            const float c1 = fmaf(-yv[k], rly, V1);
            const float c2 = fmaf( yv[k], rly, V2);

            const float sb1 = fmaf(b1, b1, 1.0f);   // 1 + b^2
            const float sb2 = fmaf(b2, b2, 1.0f);
            const float cq1 = c1 * c1;
            const float cq2 = c2 * c2;

            const float d11 = __builtin_amdgcn_sqrtf(sb1 + cq1);
            const float d12 = __builtin_amdgcn_sqrtf(sb1 + cq2);
            const float d21 = __builtin_amdgcn_sqrtf(sb2 + cq1);
            const float d22 = __builtin_amdgcn_sqrtf(sb2 + cq2);

            // ---- atan pair products (form H for the shared rcp) ----
            const float n11 = b1 * c1, n12 = b1 * c2;
            const float n21 = b2 * c1, n22 = b2 * c2;

            const float reA = fmaf(-n11, n12, d11 * d12);
            const float imA = fmaf( d11, n12, n11 * d12);
            const float reB = fmaf(-n21, n22, d21 * d22);
            const float imB = fmaf( d21, n22, n21 * d22);

            const float ayA = fabsf(imA), axA = fabsf(reA);
            const float ayB = fabsf(imB), axB = fabsf(reB);
            const float hA = fmaxf(ayA, axA), lA = fminf(ayA, axA);
            const float hB = fmaxf(ayB, axB), lB = fminf(ayB, axB);

            // ---- log numerators/denominators (ratio form) ----
            const float nu1 = c2 + d12, nu2 = c2 + d22;
            const float nu3 = b2 + d21, nu4 = b2 + d22;
            const float de1 = d11 - c1, de2 = d21 - c1;
            const float de3 = d11 - b1, de4 = d12 - b1;

            const float p12 = de1 * de2, p34 = de3 * de4;

            // ---- ONE rcp for log denoms + atan range reductions ----
            const float G = p12 * p34;
            const float H = hA * hB;
            const float RC = __builtin_amdgcn_rcpf(G * H);
            const float R  = RC * H;          // 1/G
            const float R2 = RC * G;          // 1/H

            const float R12 = R * p34, R34 = R * p12;
            const float r1 = R12 * de2, r2 = R12 * de1;
            const float r3 = R34 * de4, r4 = R34 * de3;

            float logsum =      b1 * __log2f(nu1 * r1);
            logsum = fmaf(b2, __log2f(nu2 * r2), logsum);
            logsum = fmaf(c1, __log2f(nu3 * r3), logsum);
            logsum = fmaf(c2, __log2f(nu4 * r4), logsum);

            const float tA = lA * (R2 * hB);
            const float tB = lB * (R2 * hA);

            const float pA_ = atan_poly01(tA);
            const float pB_ = atan_poly01(tB);

            float angA = (ayA > axA) ? (PI_2F - pA_) : pA_;
            angA = (reA < 0.0f) ? (PIF - angA) : angA;
            angA = __builtin_copysignf(angA, imA);

            float angB = (ayB > axB) ? (PI_2F - pB_) : pB_;
            angB = (reB < 0.0f) ? (PIF - angB) : angB;
            angB = __builtin_copysignf(angB, imB);

            const float atansum = angA + angB;

            acc[k] = fmaf(PL,  logsum,  acc[k]);
            acc[k] = fmaf(PTn, atansum, acc[k]);
        }
    }

    ((float2*)out)[pidx] = make_float2(acc[0], acc[1]);
}

extern "C" void kernel_launch(void* const* d_in, const int* in_sizes, int n_in,
                              void* d_out, int out_size, void* d_ws, size_t ws_size,
                              hipStream_t stream) {
    const float* x   = (const float*)d_in[0];
    const float* y   = (const float*)d_in[1];
    const float* cx  = (const float*)d_in[2];
    const float* cy  = (const float*)d_in[3];
    const float* cw  = (const float*)d_in[4];
    const float* chh = (const float*)d_in[5];
    const float* cp  = (const float*)d_in[6];
    const float* pA  = (const float*)d_in[7];
    const float* pa  = (const float*)d_in[8];
    const float* pB  = (const float*)d_in[9];
    const float* lx  = (const float*)d_in[10];
    const float* ly  = (const float*)d_in[11];
    float* out = (float*)d_out;
    float* ws  = (float*)d_ws;

    const int N  = in_sizes[10];            // lx has N elements
    const int B  = in_sizes[2] / N;         // chiplets_x is (B, N)
    const int G2 = in_sizes[0] / B;         // x is (B, G2)

    // precompute per-(b,i) uniforms (a-normalized)
    {
        const int total = B * N;
        dim3 pb(256, 1, 1);
        dim3 pg((total + 255) / 256, 1, 1);
        chiplet_pre_kernel<<<pg, pb, 0, stream>>>(cx, cy, cw, chh, cp,
                                                  pA, pa, pB, lx, ly, ws, B, N);
    }

    const int half = G2 / 2;
    dim3 block(256, 1, 1);
    dim3 grid((half + 255) / 256, B, 1);

    if (N == 16 && (G2 % 2) == 0) {
        chiplet_main_kernel<16><<<grid, block, 0, stream>>>(x, y, ws, out, N, G2, B);
    } else {
        chiplet_main_kernel<0><<<grid, block, 0, stream>>>(x, y, ws, out, N, G2, B);
    }
}